// Round 8
// baseline (84.543 us; speedup 1.0000x reference)
//
#include <hip/hip_runtime.h>

#define T_LEN 16384
#define R_CNT 64
#define CROP 256
#define B2_CNT 1024
#define QS 128            // samples per block
#define CDW 584           // dwords (f16 pairs) per shifted copy, pre-skew
#define CDW_S 656         // skewed allocation: 584 + 4*ceil(584/32)

typedef _Float16 h2 __attribute__((ext_vector_type(2)));

__device__ __forceinline__ h2 as_h2(unsigned u) {
    union { unsigned u; h2 h; } v; v.u = u; return v.h;
}

#if __has_builtin(__builtin_amdgcn_fdot2)
__device__ __forceinline__ float DOT2(unsigned a, unsigned b, float c) {
    return __builtin_amdgcn_fdot2(as_h2(a), as_h2(b), c, false);
}
#else
__device__ __forceinline__ float DOT2(unsigned a, unsigned b, float c) {
    h2 x = as_h2(a), y = as_h2(b);
    return fmaf((float)x[0], (float)y[0], fmaf((float)x[1], (float)y[1], c));
}
#endif

__global__ void zero_out(float* __restrict__ out) {
    out[blockIdx.x * 256 + threadIdx.x] = 0.0f;
}

__global__ __launch_bounds__(256, 6) void tof_kernel(
    const float* __restrict__ recordings,       // (B1, R, T)
    const float* __restrict__ sample_locations, // (B1, B2, 3)
    const float* __restrict__ emitter,          // (3,)
    const float* __restrict__ receivers,        // (R, 3)
    const float* __restrict__ echo,             // (CROP,)
    float* __restrict__ out)                    // (B1, B2), pre-zeroed; atomic accumulate
{
    const int blk  = blockIdx.x;              // ((b1*64)+r)*8 + qc
    const int b1   = blk >> 9;
    const int r    = (blk >> 3) & 63;
    const int qc   = blk & 7;
    const int tid  = threadIdx.x;
    const int lane = tid & 63;
    const int wave = tid >> 6;
    const int i8   = lane & 7;                // tap-owner within 8-lane group
    const int g3   = lane >> 3;               // group 0..7 (pair owner)

    // copy_c element t (f16) = row[t + c];  dword j = (w[2j+c], w[2j+c+1])
    // skew: dword j stored at j + 4*(j>>5) to break stride-16-dword bank conflicts
    __shared__ unsigned s_copy[8 * CDW_S];    // 21.0 KB
    __shared__ unsigned s_echo_pk[CROP / 2];  // 0.5 KB
    __shared__ float2   s_sf[QS];             // 1.0 KB

    // ---- stage f16-packed shifted copies of this (b1,r) row region ----
    const float* __restrict__ row = recordings + ((size_t)b1 * R_CNT + r) * T_LEN;
    #pragma unroll
    for (int c = 0; c < 8; ++c)
        for (int j = tid; j < CDW; j += 256) {
            const float a = row[c + 2 * j];
            const float b = row[c + 2 * j + 1];
            s_copy[c * CDW_S + j + 4 * (j >> 5)] =
                __builtin_bit_cast(unsigned, __builtin_amdgcn_cvt_pkrtz(a, b));
        }

    // ---- pack echo ----
    if (tid < CROP / 2)
        s_echo_pk[tid] = __builtin_bit_cast(unsigned,
            __builtin_amdgcn_cvt_pkrtz(echo[2 * tid], echo[2 * tid + 1]));

    // ---- geometry for this block's 128 samples ----
    if (tid < QS) {
        const int q = qc * QS + tid;
        const float sx = sample_locations[(b1 * B2_CNT + q) * 3 + 0];
        const float sy = sample_locations[(b1 * B2_CNT + q) * 3 + 1];
        const float sz = sample_locations[(b1 * B2_CNT + q) * 3 + 2];
        const float ex = emitter[0], ey = emitter[1], ez = emitter[2];
        const float dex = sx - ex, dey = sy - ey, dez = sz - ez;
        const float d_es = sqrtf(fmaf(dex, dex, fmaf(dey, dey, dez * dez)));
        const float rx = receivers[r * 3 + 0];
        const float ry = receivers[r * 3 + 1];
        const float rz = receivers[r * 3 + 2];
        const float dx = sx - rx, dy = sy - ry, dz = sz - rz;
        const float d_sr = sqrtf(fmaf(dx, dx, fmaf(dy, dy, dz * dz)));

        const float SCALE = 96000.0f / 343.0f;
        const float start = (d_es + d_sr) * SCALE;
        const float i0f   = floorf(start);
        int s0 = (int)i0f;
        s0 = s0 < 0 ? 0 : (s0 > 904 ? 904 : s0);   // geometry guarantees [0,904]
        s_sf[tid] = make_float2(__int_as_float(s0), start - i0f);
    }
    __syncthreads();

    // ---- echo fragments: lane i8 owns taps [32*i8, 32*i8+32) = packed dwords [16*i8, +16) ----
    unsigned e[16];
    #pragma unroll
    for (int n = 0; n < 4; ++n)
        *(uint4*)&e[4 * n] = *(const uint4*)&s_echo_pk[i8 * 16 + 4 * n];

    // ---- main: 4 passes, 8 pairs (samples) per pass ----
    for (int pass = 0; pass < 4; ++pass) {
        const int ql = wave * 32 + pass * 8 + g3;
        const float2 sf  = s_sf[ql];               // group-uniform
        const int   s0   = __float_as_int(sf.x);
        const float frac = sf.y;
        const int   c    = s0 & 7;
        const int   D    = 4 * (s0 >> 3) + 16 * i8; // dword base, pre-skew

        const unsigned* __restrict__ cb = &s_copy[c * CDW_S];

        unsigned d[17];
        #pragma unroll
        for (int n = 0; n < 4; ++n) {
            const int dj = D + 4 * n;
            *(uint4*)&d[4 * n] = *(const uint4*)&cb[dj + 4 * (dj >> 5)];
        }
        {
            const int dj = D + 16;                  // boundary dword (incl. m=256 tail)
            d[16] = cb[dj + 4 * (dj >> 5)];
        }

        float A = 0.0f, B = 0.0f;
        #pragma unroll
        for (int k = 0; k < 16; ++k) {
            A = DOT2(e[k], d[k], A);
            const unsigned sh = (d[k] >> 16) | (d[k + 1] << 16);  // v_alignbit
            B = DOT2(e[k], sh, B);
        }

        float pr = fmaf(frac, B - A, A);            // (1-f)A + fB
        pr += __shfl_xor(pr, 1);
        pr += __shfl_xor(pr, 2);
        pr += __shfl_xor(pr, 4);

        if (i8 == 0)
            atomicAdd(&out[b1 * B2_CNT + qc * QS + ql], fmaxf(pr, 0.0f));
    }
}

extern "C" void kernel_launch(void* const* d_in, const int* in_sizes, int n_in,
                              void* d_out, int out_size, void* d_ws, size_t ws_size,
                              hipStream_t stream) {
    const float* recordings       = (const float*)d_in[0]; // (4, 64, 16384)
    const float* sample_locations = (const float*)d_in[1]; // (4, 1024, 3)
    const float* emitter          = (const float*)d_in[2]; // (3,)
    const float* receivers        = (const float*)d_in[3]; // (64, 3)
    const float* echo             = (const float*)d_in[4]; // (256,)
    float* out                    = (float*)d_out;         // (4, 1024)

    const int B1 = in_sizes[1] / (B2_CNT * 3);             // = 4

    zero_out<<<dim3(B1 * B2_CNT / 256), dim3(256), 0, stream>>>(out);
    tof_kernel<<<dim3(B1 * R_CNT * 8), dim3(256), 0, stream>>>(
        recordings, sample_locations, emitter, receivers, echo, out);
}

// Round 11
// 77.701 us; speedup vs baseline: 1.0880x; 1.0880x over previous
//
#include <hip/hip_runtime.h>

#define T_LEN 16384
#define R_CNT 64
#define CROP 256
#define B2_CNT 1024
#define CDW 588            // f16-pair dwords per shifted copy (taps up to 2*587+7+1=1182)
#define CDW_S 664          // skewed allocation: 588 + 4*ceil(588/32)
#define NLAG 928           // lag-table row stride; lags [0,920) computed, [0,906) used

typedef _Float16 h2 __attribute__((ext_vector_type(2)));

__device__ __forceinline__ h2 as_h2(unsigned u) {
    union { unsigned u; h2 h; } v; v.u = u; return v.h;
}

#if __has_builtin(__builtin_amdgcn_fdot2)
__device__ __forceinline__ float DOT2(unsigned a, unsigned b, float c) {
    return __builtin_amdgcn_fdot2(as_h2(a), as_h2(b), c, false);
}
#else
__device__ __forceinline__ float DOT2(unsigned a, unsigned b, float c) {
    h2 x = as_h2(a), y = as_h2(b);
    return fmaf((float)x[0], (float)y[0], fmaf((float)x[1], (float)y[1], c));
}
#endif

// ---------------- kernel 1: per-row lag table C[j] = sum_m echo[m]*row[j+m] ----------------
// grid = (b1*64 + r)*4 + quarter ; each block computes 256 lags (guarded at 920)
__global__ __launch_bounds__(256) void corr_kernel(
    const float* __restrict__ recordings,   // (B1, R, T)
    const float* __restrict__ echo,         // (CROP,)
    float* __restrict__ C)                  // (B1, R, NLAG) in d_ws
{
    const int blk  = blockIdx.x;
    const int b1   = blk >> 8;
    const int r    = (blk >> 2) & 63;
    const int base = (blk & 3) * 256;       // lag base for this block
    const int tid  = threadIdx.x;
    const int lane = tid & 63;
    const int wave = tid >> 6;
    const int i8   = lane & 7;
    const int g3   = lane >> 3;

    // copy_c dword j = f16pack(row[c+2j], row[c+2j+1]); stored at j + 4*(j>>5) (bank skew)
    __shared__ __align__(16) unsigned s_copy[8 * CDW_S];   // 21.2 KB
    __shared__ __align__(16) unsigned s_echo_pk[CROP / 2];

    const float* __restrict__ row = recordings + ((size_t)b1 * R_CNT + r) * T_LEN;
    #pragma unroll
    for (int c = 0; c < 8; ++c)
        for (int j = tid; j < CDW; j += 256) {
            const float a = row[c + 2 * j];
            const float b = row[c + 2 * j + 1];
            s_copy[c * CDW_S + j + 4 * (j >> 5)] =
                __builtin_bit_cast(unsigned, __builtin_amdgcn_cvt_pkrtz(a, b));
        }
    if (tid < CROP / 2)
        s_echo_pk[tid] = __builtin_bit_cast(unsigned,
            __builtin_amdgcn_cvt_pkrtz(echo[2 * tid], echo[2 * tid + 1]));
    __syncthreads();

    // lane i8 holds echo packed dwords [16*i8, 16*i8+16)
    unsigned e[16];
    #pragma unroll
    for (int n = 0; n < 4; ++n)
        *(uint4*)&e[4 * n] = *(const uint4*)&s_echo_pk[i8 * 16 + 4 * n];

    const int s = wave * 8 + g3;            // group id in block, 0..31
    float* __restrict__ Crow = C + ((size_t)b1 * R_CNT + r) * NLAG;

    // each 8-lane group computes lag pair (J, J+8): same copy c=J&7, windows share LDS reads
    #pragma unroll
    for (int pass = 0; pass < 4; ++pass) {
        const int J = base + pass * 64 + (s & 7) + ((s >> 3) * 16);
        if (J < 920) {
            const int c = J & 7;
            const int b = J >> 3;
            const unsigned* __restrict__ cb = &s_copy[c * CDW_S];

            // dwords [4b+16*i8, +20): lag J uses d[0..16), lag J+8 uses d[4..20)
            unsigned d[20];
            #pragma unroll
            for (int n = 0; n < 5; ++n) {
                const int dj = 4 * b + 16 * i8 + 4 * n;
                *(uint4*)&d[4 * n] = *(const uint4*)&cb[dj + 4 * (dj >> 5)];
            }

            float a0 = 0.0f, a1 = 0.0f;
            #pragma unroll
            for (int k = 0; k < 16; ++k) {
                a0 = DOT2(e[k], d[k],     a0);
                a1 = DOT2(e[k], d[k + 4], a1);
            }
            a0 += __shfl_xor(a0, 1); a1 += __shfl_xor(a1, 1);
            a0 += __shfl_xor(a0, 2); a1 += __shfl_xor(a1, 2);
            a0 += __shfl_xor(a0, 4); a1 += __shfl_xor(a1, 4);
            if (i8 == 0) {
                Crow[J]     = a0;
                Crow[J + 8] = a1;
            }
        }
    }
}

// ---------------- kernel 2: per-pair interp + relu + sum over receivers ----------------
// grid = b1*64 + qc (16 samples each); block 256 = 16 samples x 16 r-groups (4 r each)
__global__ __launch_bounds__(256) void pair_kernel(
    const float* __restrict__ sample_locations, // (B1, B2, 3)
    const float* __restrict__ emitter,          // (3,)
    const float* __restrict__ receivers,        // (R, 3)
    const float* __restrict__ C,                // (B1, R, NLAG) in d_ws
    float* __restrict__ out)                    // (B1, B2)
{
    const int blk = blockIdx.x;
    const int b1  = blk >> 6;
    const int qc  = blk & 63;
    const int tid = threadIdx.x;
    const int ql  = tid & 15;
    const int rg  = tid >> 4;                  // 0..15, each owns 4 receivers

    __shared__ float s_recv[R_CNT * 3];
    __shared__ float s_part[16][17];

    if (tid < R_CNT * 3) s_recv[tid] = receivers[tid];
    __syncthreads();

    const int q = qc * 16 + ql;
    const float sx = sample_locations[(b1 * B2_CNT + q) * 3 + 0];
    const float sy = sample_locations[(b1 * B2_CNT + q) * 3 + 1];
    const float sz = sample_locations[(b1 * B2_CNT + q) * 3 + 2];
    const float ex = emitter[0], ey = emitter[1], ez = emitter[2];
    const float dex = sx - ex, dey = sy - ey, dez = sz - ez;
    const float d_es = sqrtf(fmaf(dex, dex, fmaf(dey, dey, dez * dez)));

    const float SCALE = 96000.0f / 343.0f;
    float acc = 0.0f;

    #pragma unroll
    for (int rr = 0; rr < 4; ++rr) {
        const int r = rg * 4 + rr;
        const float rx = s_recv[r * 3 + 0];
        const float ry = s_recv[r * 3 + 1];
        const float rz = s_recv[r * 3 + 2];
        const float dx = sx - rx, dy = sy - ry, dz = sz - rz;
        const float d_sr = sqrtf(fmaf(dx, dx, fmaf(dy, dy, dz * dz)));

        const float start = (d_es + d_sr) * SCALE;
        const float i0f   = floorf(start);
        const float frac  = start - i0f;
        int s0 = (int)i0f;
        s0 = s0 < 0 ? 0 : (s0 > 904 ? 904 : s0);   // geometry guarantees [0,904]

        const float* cp = C + ((size_t)b1 * R_CNT + r) * NLAG + s0;
        const float c0 = cp[0];
        const float c1 = cp[1];
        acc += fmaxf(fmaf(frac, c1 - c0, c0), 0.0f);
    }

    s_part[rg][ql] = acc;
    __syncthreads();

    if (tid < 16) {
        float sum = 0.0f;
        #pragma unroll
        for (int g = 0; g < 16; ++g) sum += s_part[g][tid];
        out[b1 * B2_CNT + qc * 16 + tid] = sum;
    }
}

extern "C" void kernel_launch(void* const* d_in, const int* in_sizes, int n_in,
                              void* d_out, int out_size, void* d_ws, size_t ws_size,
                              hipStream_t stream) {
    const float* recordings       = (const float*)d_in[0]; // (4, 64, 16384)
    const float* sample_locations = (const float*)d_in[1]; // (4, 1024, 3)
    const float* emitter          = (const float*)d_in[2]; // (3,)
    const float* receivers        = (const float*)d_in[3]; // (64, 3)
    const float* echo             = (const float*)d_in[4]; // (256,)
    float* out                    = (float*)d_out;         // (4, 1024)
    float* C                      = (float*)d_ws;          // (4, 64, NLAG) = 950 KB

    const int B1 = in_sizes[1] / (B2_CNT * 3);             // = 4

    corr_kernel<<<dim3(B1 * R_CNT * 4), dim3(256), 0, stream>>>(recordings, echo, C);
    pair_kernel<<<dim3(B1 * 64), dim3(256), 0, stream>>>(sample_locations, emitter,
                                                         receivers, C, out);
}

// Round 13
// 74.575 us; speedup vs baseline: 1.1337x; 1.0419x over previous
//
#include <hip/hip_runtime.h>

#define T_LEN 16384
#define R_CNT 64
#define CROP 256
#define B2_CNT 1024
#define CDW_Q 260          // f16-pair dwords per shifted copy (quarter window: taps [base, base+520))
#define CDW_QS 296         // skewed allocation: 260 + 4*ceil(260/32)
#define NLAG 928           // lag-table row stride; lags [0,920) computed, [0,906) used

typedef _Float16 h2 __attribute__((ext_vector_type(2)));

__device__ __forceinline__ h2 as_h2(unsigned u) {
    union { unsigned u; h2 h; } v; v.u = u; return v.h;
}

#if __has_builtin(__builtin_amdgcn_fdot2)
__device__ __forceinline__ float DOT2(unsigned a, unsigned b, float c) {
    return __builtin_amdgcn_fdot2(as_h2(a), as_h2(b), c, false);
}
#else
__device__ __forceinline__ float DOT2(unsigned a, unsigned b, float c) {
    h2 x = as_h2(a), y = as_h2(b);
    return fmaf((float)x[0], (float)y[0], fmaf((float)x[1], (float)y[1], c));
}
#endif

// ---------------- kernel 1: per-row lag table C[j] = sum_m echo[m]*row[j+m] ----------------
// grid = (b1*64 + r)*4 + quarter ; block computes lags [base, base+256) (guarded at 920)
__global__ __launch_bounds__(256) void corr_kernel(
    const float* __restrict__ recordings,   // (B1, R, T)
    const float* __restrict__ echo,         // (CROP,)
    float* __restrict__ C)                  // (B1, R, NLAG) in d_ws
{
    const int blk  = blockIdx.x;
    const int b1   = blk >> 8;
    const int r    = (blk >> 2) & 63;
    const int base = (blk & 3) * 256;       // lag base for this block
    const int tid  = threadIdx.x;
    const int lane = tid & 63;
    const int wave = tid >> 6;
    const int i8   = lane & 7;
    const int g3   = lane >> 3;

    // copy_c dword j = f16pack(row[base+c+2j], row[base+c+2j+1]); stored at j + 4*(j>>5)
    __shared__ __align__(16) unsigned s_copy[8 * CDW_QS];  // 9.5 KB
    __shared__ __align__(16) unsigned s_echo_pk[CROP / 2];

    const float* __restrict__ row = recordings + ((size_t)b1 * R_CNT + r) * T_LEN + base;
    #pragma unroll
    for (int c = 0; c < 8; ++c)
        for (int j = tid; j < CDW_Q; j += 256) {
            const float a = row[c + 2 * j];
            const float b = row[c + 2 * j + 1];
            s_copy[c * CDW_QS + j + 4 * (j >> 5)] =
                __builtin_bit_cast(unsigned, __builtin_amdgcn_cvt_pkrtz(a, b));
        }
    if (tid < CROP / 2)
        s_echo_pk[tid] = __builtin_bit_cast(unsigned,
            __builtin_amdgcn_cvt_pkrtz(echo[2 * tid], echo[2 * tid + 1]));
    __syncthreads();

    // lane i8 holds echo packed dwords [16*i8, 16*i8+16)
    unsigned e[16];
    #pragma unroll
    for (int n = 0; n < 4; ++n)
        *(uint4*)&e[4 * n] = *(const uint4*)&s_echo_pk[i8 * 16 + 4 * n];

    const int s = wave * 8 + g3;            // group id in block, 0..31
    float* __restrict__ Crow = C + ((size_t)b1 * R_CNT + r) * NLAG;

    // each 8-lane group computes 4 lags {Jl, Jl+8, Jl+16, Jl+24}: shared copy c, 7 b128 reads
    #pragma unroll
    for (int pass = 0; pass < 2; ++pass) {
        const int Jl = (s & 7) + ((s >> 3) * 32) + pass * 128;  // local lag of group base
        const int c  = Jl & 7;
        const int b  = Jl >> 3;
        const unsigned* __restrict__ cb = &s_copy[c * CDW_QS];

        // dwords [4b+16*i8, +28): lag Jl+8t uses d[4t .. 4t+16)
        unsigned d[28];
        #pragma unroll
        for (int n = 0; n < 7; ++n) {
            const int dj = 4 * b + 16 * i8 + 4 * n;
            *(uint4*)&d[4 * n] = *(const uint4*)&cb[dj + 4 * (dj >> 5)];
        }

        float a0 = 0.0f, a1 = 0.0f, a2 = 0.0f, a3 = 0.0f;
        #pragma unroll
        for (int k = 0; k < 16; ++k) {
            a0 = DOT2(e[k], d[k],      a0);
            a1 = DOT2(e[k], d[k + 4],  a1);
            a2 = DOT2(e[k], d[k + 8],  a2);
            a3 = DOT2(e[k], d[k + 12], a3);
        }
        #pragma unroll
        for (int off = 1; off <= 4; off <<= 1) {
            a0 += __shfl_xor(a0, off);
            a1 += __shfl_xor(a1, off);
            a2 += __shfl_xor(a2, off);
            a3 += __shfl_xor(a3, off);
        }
        if (i8 == 0) {
            const int J = base + Jl;
            if (J      < 920) Crow[J]      = a0;
            if (J + 8  < 920) Crow[J + 8]  = a1;
            if (J + 16 < 920) Crow[J + 16] = a2;
            if (J + 24 < 920) Crow[J + 24] = a3;
        }
    }
}

// ---------------- kernel 2: per-pair interp + relu + sum over receivers ----------------
// grid = b1*64 + qc (16 samples each); block 256 = 16 samples x 16 r-groups (4 r each)
__global__ __launch_bounds__(256) void pair_kernel(
    const float* __restrict__ sample_locations, // (B1, B2, 3)
    const float* __restrict__ emitter,          // (3,)
    const float* __restrict__ receivers,        // (R, 3)
    const float* __restrict__ C,                // (B1, R, NLAG) in d_ws
    float* __restrict__ out)                    // (B1, B2)
{
    const int blk = blockIdx.x;
    const int b1  = blk >> 6;
    const int qc  = blk & 63;
    const int tid = threadIdx.x;
    const int ql  = tid & 15;
    const int rg  = tid >> 4;                  // 0..15, each owns 4 receivers

    __shared__ float s_recv[R_CNT * 3];
    __shared__ float s_part[16][17];

    if (tid < R_CNT * 3) s_recv[tid] = receivers[tid];
    __syncthreads();

    const int q = qc * 16 + ql;
    const float sx = sample_locations[(b1 * B2_CNT + q) * 3 + 0];
    const float sy = sample_locations[(b1 * B2_CNT + q) * 3 + 1];
    const float sz = sample_locations[(b1 * B2_CNT + q) * 3 + 2];
    const float ex = emitter[0], ey = emitter[1], ez = emitter[2];
    const float dex = sx - ex, dey = sy - ey, dez = sz - ez;
    const float d_es = sqrtf(fmaf(dex, dex, fmaf(dey, dey, dez * dez)));

    const float SCALE = 96000.0f / 343.0f;
    float acc = 0.0f;

    #pragma unroll
    for (int rr = 0; rr < 4; ++rr) {
        const int r = rg * 4 + rr;
        const float rx = s_recv[r * 3 + 0];
        const float ry = s_recv[r * 3 + 1];
        const float rz = s_recv[r * 3 + 2];
        const float dx = sx - rx, dy = sy - ry, dz = sz - rz;
        const float d_sr = sqrtf(fmaf(dx, dx, fmaf(dy, dy, dz * dz)));

        const float start = (d_es + d_sr) * SCALE;
        const float i0f   = floorf(start);
        const float frac  = start - i0f;
        int s0 = (int)i0f;
        s0 = s0 < 0 ? 0 : (s0 > 904 ? 904 : s0);   // geometry guarantees [0,904]

        const float* cp = C + ((size_t)b1 * R_CNT + r) * NLAG + s0;
        const float c0 = cp[0];
        const float c1 = cp[1];
        acc += fmaxf(fmaf(frac, c1 - c0, c0), 0.0f);
    }

    s_part[rg][ql] = acc;
    __syncthreads();

    if (tid < 16) {
        float sum = 0.0f;
        #pragma unroll
        for (int g = 0; g < 16; ++g) sum += s_part[g][tid];
        out[b1 * B2_CNT + qc * 16 + tid] = sum;
    }
}

extern "C" void kernel_launch(void* const* d_in, const int* in_sizes, int n_in,
                              void* d_out, int out_size, void* d_ws, size_t ws_size,
                              hipStream_t stream) {
    const float* recordings       = (const float*)d_in[0]; // (4, 64, 16384)
    const float* sample_locations = (const float*)d_in[1]; // (4, 1024, 3)
    const float* emitter          = (const float*)d_in[2]; // (3,)
    const float* receivers        = (const float*)d_in[3]; // (64, 3)
    const float* echo             = (const float*)d_in[4]; // (256,)
    float* out                    = (float*)d_out;         // (4, 1024)
    float* C                      = (float*)d_ws;          // (4, 64, NLAG) = 950 KB

    const int B1 = in_sizes[1] / (B2_CNT * 3);             // = 4

    corr_kernel<<<dim3(B1 * R_CNT * 4), dim3(256), 0, stream>>>(recordings, echo, C);
    pair_kernel<<<dim3(B1 * 64), dim3(256), 0, stream>>>(sample_locations, emitter,
                                                         receivers, C, out);
}

// Round 14
// 74.546 us; speedup vs baseline: 1.1341x; 1.0004x over previous
//
#include <hip/hip_runtime.h>

#define T_LEN 16384
#define R_CNT 64
#define CROP 256
#define B2_CNT 1024
#define CDW_Q 260          // f16-pair dwords per shifted copy (quarter window: taps [base, base+520))
#define CDW_QS 296         // skewed allocation: 260 + 4*ceil(260/32)
#define NLAG 928           // lag-table row stride; lags [0,920) computed, [0,906) used

typedef _Float16 h2 __attribute__((ext_vector_type(2)));

__device__ __forceinline__ h2 as_h2(unsigned u) {
    union { unsigned u; h2 h; } v; v.u = u; return v.h;
}

__device__ __forceinline__ unsigned pk(float a, float b) {
    return __builtin_bit_cast(unsigned, __builtin_amdgcn_cvt_pkrtz(a, b));
}

#if __has_builtin(__builtin_amdgcn_fdot2)
__device__ __forceinline__ float DOT2(unsigned a, unsigned b, float c) {
    return __builtin_amdgcn_fdot2(as_h2(a), as_h2(b), c, false);
}
#else
__device__ __forceinline__ float DOT2(unsigned a, unsigned b, float c) {
    h2 x = as_h2(a), y = as_h2(b);
    return fmaf((float)x[0], (float)y[0], fmaf((float)x[1], (float)y[1], c));
}
#endif

// ---------------- kernel 1: per-row lag table C[j] = sum_m echo[m]*row[j+m] ----------------
// grid = (b1*64 + r)*4 + quarter ; block computes lags [base, base+256) (guarded at 920)
__global__ __launch_bounds__(256) void corr_kernel(
    const float* __restrict__ recordings,   // (B1, R, T)
    const float* __restrict__ echo,         // (CROP,)
    float* __restrict__ C)                  // (B1, R, NLAG) in d_ws
{
    const int blk  = blockIdx.x;
    const int b1   = blk >> 8;
    const int r    = (blk >> 2) & 63;
    const int base = (blk & 3) * 256;       // lag base for this block
    const int tid  = threadIdx.x;
    const int lane = tid & 63;
    const int wave = tid >> 6;
    const int i8   = lane & 7;
    const int g3   = lane >> 3;

    // copy_c dword j = f16pack(row[base+c+2j], row[base+c+2j+1]); stored at j + 4*(j>>5)
    // identity: copy_{2d}[j] = u[d+j], copy_{2d+1}[j] = v[d+j]
    //           u_k = pk(w[2k], w[2k+1]), v_k = pk(w[2k+1], w[2k+2])
    __shared__ __align__(16) unsigned s_copy[8 * CDW_QS];  // 9.5 KB
    __shared__ __align__(16) unsigned s_echo_pk[CROP / 2];

    const float* __restrict__ row = recordings + ((size_t)b1 * R_CNT + r) * T_LEN + base;

    if (tid < 132) {
        // thread t covers u/v dwords k = 2t, 2t+1 from floats w[4t .. 4t+4]
        const float4 w4  = *reinterpret_cast<const float4*>(&row[4 * tid]);  // 16B-aligned
        const float  w4e = row[4 * tid + 4];
        const unsigned u0 = pk(w4.x, w4.y);
        const unsigned u1 = pk(w4.z, w4.w);
        const unsigned v0 = pk(w4.y, w4.z);
        const unsigned v1 = pk(w4.w, w4e);
        const int k0 = 2 * tid;
        #pragma unroll
        for (int d = 0; d < 4; ++d) {
            const int j0 = k0 - d;
            const int j1 = k0 + 1 - d;
            if (j0 >= 0 && j0 < CDW_Q) {
                const int sj0 = j0 + 4 * (j0 >> 5);
                s_copy[(2 * d)     * CDW_QS + sj0] = u0;
                s_copy[(2 * d + 1) * CDW_QS + sj0] = v0;
            }
            if (j1 >= 0 && j1 < CDW_Q) {
                const int sj1 = j1 + 4 * (j1 >> 5);
                s_copy[(2 * d)     * CDW_QS + sj1] = u1;
                s_copy[(2 * d + 1) * CDW_QS + sj1] = v1;
            }
        }
    } else if (tid >= 128) {
        const int t = tid - 128;            // 4..127 (t<4 done by nobody? no: 128..131 stage)
        if (t >= 4) s_echo_pk[t] = pk(echo[2 * t], echo[2 * t + 1]);
    }
    if (tid < 4) s_echo_pk[tid] = pk(echo[2 * tid], echo[2 * tid + 1]);
    __syncthreads();

    // lane i8 holds echo packed dwords [16*i8, 16*i8+16)
    unsigned e[16];
    #pragma unroll
    for (int n = 0; n < 4; ++n)
        *(uint4*)&e[4 * n] = *(const uint4*)&s_echo_pk[i8 * 16 + 4 * n];

    const int s = wave * 8 + g3;            // group id in block, 0..31
    float* __restrict__ Crow = C + ((size_t)b1 * R_CNT + r) * NLAG;

    // each 8-lane group computes 4 lags {Jl, Jl+8, Jl+16, Jl+24}: shared copy c, 7 b128 reads
    #pragma unroll
    for (int pass = 0; pass < 2; ++pass) {
        const int Jl = (s & 7) + ((s >> 3) * 32) + pass * 128;  // local lag of group base
        const int c  = Jl & 7;
        const int b  = Jl >> 3;
        const unsigned* __restrict__ cb = &s_copy[c * CDW_QS];

        // dwords [4b+16*i8, +28): lag Jl+8t uses d[4t .. 4t+16)
        unsigned d[28];
        #pragma unroll
        for (int n = 0; n < 7; ++n) {
            const int dj = 4 * b + 16 * i8 + 4 * n;
            *(uint4*)&d[4 * n] = *(const uint4*)&cb[dj + 4 * (dj >> 5)];
        }

        float a0 = 0.0f, a1 = 0.0f, a2 = 0.0f, a3 = 0.0f;
        #pragma unroll
        for (int k = 0; k < 16; ++k) {
            a0 = DOT2(e[k], d[k],      a0);
            a1 = DOT2(e[k], d[k + 4],  a1);
            a2 = DOT2(e[k], d[k + 8],  a2);
            a3 = DOT2(e[k], d[k + 12], a3);
        }
        #pragma unroll
        for (int off = 1; off <= 4; off <<= 1) {
            a0 += __shfl_xor(a0, off);
            a1 += __shfl_xor(a1, off);
            a2 += __shfl_xor(a2, off);
            a3 += __shfl_xor(a3, off);
        }
        if (i8 == 0) {
            const int J = base + Jl;
            if (J      < 920) Crow[J]      = a0;
            if (J + 8  < 920) Crow[J + 8]  = a1;
            if (J + 16 < 920) Crow[J + 16] = a2;
            if (J + 24 < 920) Crow[J + 24] = a3;
        }
    }
}

// ---------------- kernel 2: per-pair interp + relu + sum over receivers ----------------
// grid = b1*64 + qc (16 samples each); block 256 = 16 samples x 16 r-groups (4 r each)
__global__ __launch_bounds__(256) void pair_kernel(
    const float* __restrict__ sample_locations, // (B1, B2, 3)
    const float* __restrict__ emitter,          // (3,)
    const float* __restrict__ receivers,        // (R, 3)
    const float* __restrict__ C,                // (B1, R, NLAG) in d_ws
    float* __restrict__ out)                    // (B1, B2)
{
    const int blk = blockIdx.x;
    const int b1  = blk >> 6;
    const int qc  = blk & 63;
    const int tid = threadIdx.x;
    const int ql  = tid & 15;
    const int rg  = tid >> 4;                  // 0..15, each owns 4 receivers

    __shared__ float s_recv[R_CNT * 3];
    __shared__ float s_part[16][17];

    if (tid < R_CNT * 3) s_recv[tid] = receivers[tid];
    __syncthreads();

    const int q = qc * 16 + ql;
    const float sx = sample_locations[(b1 * B2_CNT + q) * 3 + 0];
    const float sy = sample_locations[(b1 * B2_CNT + q) * 3 + 1];
    const float sz = sample_locations[(b1 * B2_CNT + q) * 3 + 2];
    const float ex = emitter[0], ey = emitter[1], ez = emitter[2];
    const float dex = sx - ex, dey = sy - ey, dez = sz - ez;
    const float d_es = sqrtf(fmaf(dex, dex, fmaf(dey, dey, dez * dez)));

    const float SCALE = 96000.0f / 343.0f;
    float acc = 0.0f;

    #pragma unroll
    for (int rr = 0; rr < 4; ++rr) {
        const int r = rg * 4 + rr;
        const float rx = s_recv[r * 3 + 0];
        const float ry = s_recv[r * 3 + 1];
        const float rz = s_recv[r * 3 + 2];
        const float dx = sx - rx, dy = sy - ry, dz = sz - rz;
        const float d_sr = sqrtf(fmaf(dx, dx, fmaf(dy, dy, dz * dz)));

        const float start = (d_es + d_sr) * SCALE;
        const float i0f   = floorf(start);
        const float frac  = start - i0f;
        int s0 = (int)i0f;
        s0 = s0 < 0 ? 0 : (s0 > 904 ? 904 : s0);   // geometry guarantees [0,904]

        const float* cp = C + ((size_t)b1 * R_CNT + r) * NLAG + s0;
        const float c0 = cp[0];
        const float c1 = cp[1];
        acc += fmaxf(fmaf(frac, c1 - c0, c0), 0.0f);
    }

    s_part[rg][ql] = acc;
    __syncthreads();

    if (tid < 16) {
        float sum = 0.0f;
        #pragma unroll
        for (int g = 0; g < 16; ++g) sum += s_part[g][tid];
        out[b1 * B2_CNT + qc * 16 + tid] = sum;
    }
}

extern "C" void kernel_launch(void* const* d_in, const int* in_sizes, int n_in,
                              void* d_out, int out_size, void* d_ws, size_t ws_size,
                              hipStream_t stream) {
    const float* recordings       = (const float*)d_in[0]; // (4, 64, 16384)
    const float* sample_locations = (const float*)d_in[1]; // (4, 1024, 3)
    const float* emitter          = (const float*)d_in[2]; // (3,)
    const float* receivers        = (const float*)d_in[3]; // (64, 3)
    const float* echo             = (const float*)d_in[4]; // (256,)
    float* out                    = (float*)d_out;         // (4, 1024)
    float* C                      = (float*)d_ws;          // (4, 64, NLAG) = 950 KB

    const int B1 = in_sizes[1] / (B2_CNT * 3);             // = 4

    corr_kernel<<<dim3(B1 * R_CNT * 4), dim3(256), 0, stream>>>(recordings, echo, C);
    pair_kernel<<<dim3(B1 * 64), dim3(256), 0, stream>>>(sample_locations, emitter,
                                                         receivers, C, out);
}